// Round 7
// baseline (15389.748 us; speedup 1.0000x reference)
//
#include <hip/hip_runtime.h>
#include <hip/hip_bf16.h>
#include <math.h>

typedef __hip_bfloat16 bf16;
#define DEV __device__ __forceinline__

DEV float tofl(float v){ return v; }
DEV float tofl(bf16 v){ return __bfloat162float(v); }
DEV bf16  f2b(float v){ return __float2bfloat16(v); }
DEV void  stout(float* p, float v){ *p = v; }
DEV void  stout(bf16*  p, float v){ *p = f2b(v); }

static constexpr int Cc=256, Nn=4096, Mm=32;
static constexpr size_t ACT = (size_t)8*Cc*Nn;   // 8,388,608 elems per output tensor
static constexpr float EPSc = 1e-6f;

enum { EPI_NONE=0, EPI_SOFTPLUS=1 };

// ---- literal 1x1 conv: out[b,o,n] = epi( sum_k in[b,k,n] * w[o*K+k] ), one thread/elem
template<int EPI, typename TOUT>
__global__ __launch_bounds__(256) void c1_lit(const float* __restrict__ in,
    const float* __restrict__ w, TOUT* __restrict__ out, int K, int O)
{
  size_t idx = (size_t)blockIdx.x*256 + threadIdx.x;   // ((b*O+o)<<12)+n
  int n = (int)(idx & 4095);
  int o = (int)((idx >> 12) % O);
  int b = (int)(idx / ((size_t)O << 12));
  const float* inb = in + ((size_t)b*K << 12) + n;
  const float* wr  = w + (size_t)o*K;
  float a = 0.f;
  for(int k=0;k<K;k++) a += inb[(size_t)k<<12] * wr[k];
  if (EPI==EPI_SOFTPLUS) a = fmaxf(a,0.f) + log1pf(expf(-fabsf(a)));
  stout(&out[idx], a);
}

// ---- literal depthwise 3x3 (zero pad) + conv_bn + norm affine, fp32->fp32
__global__ __launch_bounds__(256) void dw_norm_lit(const float* __restrict__ pw,
    float* __restrict__ z1, const float* __restrict__ dww,
    const float* __restrict__ cbs, const float* __restrict__ cbt,
    const float* __restrict__ ns, const float* __restrict__ nt)
{
  size_t idx = (size_t)blockIdx.x*256 + threadIdx.x;   // b*C*N + c*N + n
  int n = (int)(idx & 4095);
  int c = (int)((idx>>12) & 255);
  int h = n>>6, wq = n&63;
  const float* p = pw + (idx - n);
  float acc = 0.f;
  for(int i=0;i<3;i++){
    int hh = h+i-1; if((unsigned)hh >= 64u) continue;
    for(int j=0;j<3;j++){
      int ww = wq+j-1; if((unsigned)ww >= 64u) continue;
      acc += dww[c*9 + i*3 + j] * p[hh*64 + ww];
    }
  }
  float bn = acc*cbs[c] + cbt[c];        // conv BN
  z1[idx] = bn*ns[c] + nt[c];            // norm BN
}

// ---- literal row-dot: out[x] = sum_n A[b,i,:]·B[b,j,:], x = (b*rowsA+i)*rowsB+j
__global__ __launch_bounds__(256) void rowdot_lit(const float* __restrict__ A,
    const float* __restrict__ B, float* __restrict__ out, int rowsA, int rowsB)
{
  int x = blockIdx.x;
  int j = x % rowsB; int t = x / rowsB; int i = t % rowsA; int b = t / rowsA;
  const float* ar = A + (((size_t)b*rowsA + i) << 12);
  const float* br = B + (((size_t)b*rowsB + j) << 12);
  float a = 0.f;
  for(int n=threadIdx.x; n<Nn; n+=256) a += ar[n]*br[n];
  __shared__ float red[4];
  for(int off=32;off;off>>=1) a += __shfl_down(a,off);
  int lane = threadIdx.x&63, wid = threadIdx.x>>6;
  if(lane==0) red[wid]=a;
  __syncthreads();
  if(threadIdx.x==0) out[x] = red[0]+red[1]+red[2]+red[3];
}

// ---- literal row sum over n: out[x] = sum_n A[x,:], x = b*rows+i
__global__ __launch_bounds__(256) void rowsum_lit(const float* __restrict__ A, float* __restrict__ out)
{
  int x = blockIdx.x;
  const float* ar = A + ((size_t)x << 12);
  float a = 0.f;
  for(int n=threadIdx.x; n<Nn; n+=256) a += ar[n];
  __shared__ float red[4];
  for(int off=32;off;off>>=1) a += __shfl_down(a,off);
  int lane = threadIdx.x&63, wid = threadIdx.x>>6;
  if(lane==0) red[wid]=a;
  __syncthreads();
  if(threadIdx.x==0) out[x] = red[0]+red[1]+red[2]+red[3];
}

// ---- literal inv: inv[b,n] = 1 / sum_m Q[b,m,n]*(Ks[b,m]+EPS)
__global__ __launch_bounds__(256) void inv_lit(const float* __restrict__ Qf,
    const float* __restrict__ Ks, float* __restrict__ invb)
{
  size_t idx = (size_t)blockIdx.x*256 + threadIdx.x;  // b*N + n
  int b = (int)(idx>>12), n = (int)(idx&4095);
  const float* qb = Qf + ((size_t)b*Mm << 12) + n;
  const float* ks = Ks + b*Mm;
  float s = 0.f;
  for(int m=0;m<Mm;m++) s += qb[(size_t)m<<12]*(ks[m]+EPSc);
  invb[idx] = 1.f/s;
}

// ---- literal softmax of (rowmax - e) over last axis, in place. One block per row.
__global__ __launch_bounds__(256) void softmax_lit(float* __restrict__ E)
{
  float* e = E + ((size_t)blockIdx.x << 8);   // row of 256
  int d = threadIdx.x;
  float ed = e[d];
  __shared__ float red[4];
  int lane = d&63, wid = d>>6;
  float v = ed;                                      // rowmax of energy
  for(int off=32;off;off>>=1) v = fmaxf(v, __shfl_down(v,off));
  if(lane==0) red[wid]=v;
  __syncthreads();
  float rowmax = fmaxf(fmaxf(red[0],red[1]),fmaxf(red[2],red[3]));
  __syncthreads();
  float s = rowmax - ed;                             // softmax argument
  float v2 = s;                                      // its own max (literal softmax)
  for(int off=32;off;off>>=1) v2 = fmaxf(v2, __shfl_down(v2,off));
  if(lane==0) red[wid]=v2;
  __syncthreads();
  float smax = fmaxf(fmaxf(red[0],red[1]),fmaxf(red[2],red[3]));
  __syncthreads();
  float p = expf(s - smax);
  float sv = p;
  for(int off=32;off;off>>=1) sv += __shfl_down(sv,off);
  if(lane==0) red[wid]=sv;
  __syncthreads();
  float sum = red[0]+red[1]+red[2]+red[3];
  e[d] = p/sum;
}

// ---- literal light+px: px[b,c,n] = (other*(2z + gc*sum_d att[c,d]z[d,n]
//                                   + gk*inv[n]*sum_m Q[m,n]KV[m,c]))*ns[c]+nt[c]
__global__ __launch_bounds__(256) void catt_px_lit(const float* __restrict__ z1,
    const float* __restrict__ other, const float* __restrict__ Qf,
    const float* __restrict__ KVf, const float* __restrict__ invb,
    const float* __restrict__ att, const float* __restrict__ gkp,
    const float* __restrict__ gcp, const float* __restrict__ ns,
    const float* __restrict__ nt, bf16* __restrict__ px)
{
  size_t idx = (size_t)blockIdx.x*256 + threadIdx.x;  // b*C*N + c*N + n
  int n = (int)(idx & 4095);
  int c = (int)((idx>>12) & 255);
  int b = (int)(idx>>20);
  const float* ar = att + (((size_t)b<<8) + c)*256;
  const float* zb = z1 + ((size_t)b*Cc << 12) + n;
  float s1 = 0.f;
  for(int d=0; d<Cc; d++) s1 += ar[d]*zb[(size_t)d<<12];
  const float* qb  = Qf  + ((size_t)b*Mm << 12) + n;
  const float* kvb = KVf + ((size_t)b*Mm << 8) + c;
  float s2 = 0.f;
  for(int m=0;m<Mm;m++) s2 += qb[(size_t)m<<12]*kvb[(size_t)m<<8];
  float a = 2.f*z1[idx] + gcp[0]*s1 + gkp[0]*s2*invb[((size_t)b<<12)+n];
  px[idx] = f2b(other[idx]*a*ns[c] + nt[c]);
}

// ---- literal fc1 chunk: hid[b,o,n] = relu6((sum_k px[b,k,n]*w1[(o0+o)*256+k]+b1)*s1+t1)
__global__ __launch_bounds__(256) void fc1_lit(const bf16* __restrict__ px,
    const float* __restrict__ w1, float* __restrict__ hid,
    const float* __restrict__ b1, const float* __restrict__ s1,
    const float* __restrict__ t1, int o0)
{
  size_t idx = (size_t)blockIdx.x*256 + threadIdx.x;  // b*256*N + o*N + n (o chunk-local)
  int n = (int)(idx & 4095);
  int o = (int)((idx>>12) & 255);
  int b = (int)(idx>>20);
  const bf16* pb = px + ((size_t)b*Cc << 12) + n;
  const float* wr = w1 + (size_t)(o0+o)*256;
  float a = 0.f;
  for(int k=0;k<Cc;k++) a += tofl(pb[(size_t)k<<12])*wr[k];
  a = (a + b1[o0+o])*s1[o0+o] + t1[o0+o];
  hid[idx] = fminf(fmaxf(a,0.f),6.f);
}

// ---- literal fc2 chunk accumulate: acc[b,c,n] (+)= sum_k hid[b,k,n]*w2[c*1024+k0+k]
template<int INIT>
__global__ __launch_bounds__(256) void fc2_lit(const float* __restrict__ hid,
    const float* __restrict__ w2, float* __restrict__ acc, int k0)
{
  size_t idx = (size_t)blockIdx.x*256 + threadIdx.x;  // b*C*N + c*N + n
  int n = (int)(idx & 4095);
  int c = (int)((idx>>12) & 255);
  int b = (int)(idx>>20);
  const float* hb = hid + ((size_t)b*Cc << 12) + n;
  const float* wr = w2 + (size_t)c*1024 + k0;
  float a = 0.f;
  for(int k=0;k<Cc;k++) a += hb[(size_t)k<<12]*wr[k];
  if (INIT) acc[idx] = a; else acc[idx] += a;
}

// ---- outputs are FP32 (reference returns float32; comparison is done at bf16 precision)
__global__ __launch_bounds__(256) void final_y(const float* __restrict__ yin,
    const float* __restrict__ acc, const float* __restrict__ b2,
    const float* __restrict__ s2, const float* __restrict__ t2, float* __restrict__ out)
{
  size_t idx = (size_t)blockIdx.x*256 + threadIdx.x;
  int c = (int)((idx>>12) & 255);
  float y2 = (acc[idx] + b2[c])*s2[c] + t2[c];
  out[ACT + idx] = yin[idx] + y2;
}

__global__ __launch_bounds__(256) void final_x(const float* __restrict__ xin,
    const float* __restrict__ acc, const float* __restrict__ b2,
    const float* __restrict__ s2, const float* __restrict__ t2, float* __restrict__ out)
{
  size_t idx = (size_t)blockIdx.x*256 + threadIdx.x;
  int c = (int)((idx>>12) & 255);
  float x2 = (acc[idx] + b2[c])*s2[c] + t2[c];
  out[idx] = xin[idx] + x2 + out[ACT + idx];
}

extern "C" void kernel_launch(void* const* d_in, const int* in_sizes, int n_in,
                              void* d_out, int out_size, void* d_ws, size_t ws_size,
                              hipStream_t stream)
{
  (void)in_sizes; (void)n_in; (void)out_size; (void)ws_size;
  const float* xin  = (const float*)d_in[0];
  const float* yin  = (const float*)d_in[1];
  const float* pw_w = (const float*)d_in[2];
  const float* dw_w = (const float*)d_in[3];
  const float* cbs  = (const float*)d_in[4];
  const float* cbt  = (const float*)d_in[5];
  const float* ns   = (const float*)d_in[6];
  const float* nt   = (const float*)d_in[7];
  const float* q_w  = (const float*)d_in[8];
  const float* k_w  = (const float*)d_in[9];
  const float* v_w  = (const float*)d_in[10];
  const float* gk   = (const float*)d_in[11];
  const float* gc   = (const float*)d_in[12];
  const float* fc1_w= (const float*)d_in[13];
  const float* fc1_b= (const float*)d_in[14];
  const float* bn1s = (const float*)d_in[15];
  const float* bn1t = (const float*)d_in[16];
  const float* fc2_w= (const float*)d_in[17];
  const float* fc2_b= (const float*)d_in[18];
  const float* bn2s = (const float*)d_in[19];
  const float* bn2t = (const float*)d_in[20];

  char* ws = (char*)d_ws;
  // ---- layout identical to round 6 (proven deterministic/safe) ----
  float* A    = (float*)(ws);                 // 0..32M: pw scratch / V / hid chunk
  float* x1   = (float*)(ws + 33554432);      // 32..64M fp32 [B,C,N]
  float* y1   = (float*)(ws + 67108864);      // 64..96M
  bf16*  px_y = (bf16*) (ws + 100663296);     // 96..112M bf16
  bf16*  px_x = (bf16*) (ws + 117440512);     // 112..128M bf16
  float* Qf   = (float*)(ws + 134217728);     // 128..132M fp32 [B,32,N]
  float* Kf   = (float*)(ws + 138412032);     // 132..136M
  float* Eng  = (float*)(ws + 142606336);     // 136..138M fp32 [B,256,256]
  float* KVf  = (float*)(ws + 144703488);     // 256K fp32 [B,32,256]
  float* Ksf  = (float*)(ws + 144965632);     // 1K  [B,32]
  float* invb = (float*)(ws + 144966656);     // 128K [B,N]
  float* accb = (float*)(ws + 33554432);      // phase3: overlays dead x1

  dim3 blk(256);

  // Phase 1: z1 = norm(bn(dw3(pw(z))))  (all fp32)
  c1_lit<EPI_NONE,float><<<dim3(32768),blk,0,stream>>>(xin, pw_w, A, 256, 256);
  dw_norm_lit<<<dim3(32768),blk,0,stream>>>(A, x1, dw_w, cbs, cbt, ns, nt);
  c1_lit<EPI_NONE,float><<<dim3(32768),blk,0,stream>>>(yin, pw_w, A, 256, 256);
  dw_norm_lit<<<dim3(32768),blk,0,stream>>>(A, y1, dw_w, cbs, cbt, ns, nt);

  // Phase 2: t=0: a=light(x1) -> px_y=(y1*a)*ns+nt ; t=1: a=light(y1) -> px_x
  for (int t=0;t<2;t++){
    const float* z1    = (t==0) ? x1 : y1;
    const float* other = (t==0) ? y1 : x1;
    bf16* pxout        = (t==0) ? px_y : px_x;
    c1_lit<EPI_SOFTPLUS,float><<<dim3(4096),blk,0,stream>>>(z1, q_w, Qf, 256, 32);
    c1_lit<EPI_SOFTPLUS,float><<<dim3(4096),blk,0,stream>>>(z1, k_w, Kf, 256, 32);
    c1_lit<EPI_NONE,float><<<dim3(32768),blk,0,stream>>>(z1, v_w, A, 256, 256);   // V
    rowdot_lit<<<dim3(65536),blk,0,stream>>>(Kf, A, KVf, 32, 256);                // KV[b,m,c]
    rowsum_lit<<<dim3(256),blk,0,stream>>>(Kf, Ksf);                              // K.sum(-1)
    inv_lit<<<dim3(128),blk,0,stream>>>(Qf, Ksf, invb);
    rowdot_lit<<<dim3(524288),blk,0,stream>>>(z1, z1, Eng, 256, 256);             // energy
    softmax_lit<<<dim3(2048),blk,0,stream>>>(Eng);                                // att in place
    catt_px_lit<<<dim3(32768),blk,0,stream>>>(z1, other, Qf, KVf, invb, Eng,
                                              gk, gc, ns, nt, pxout);
  }

  // Phase 3: MLPs (4 K-chunks; hid chunk fp32 in A, fp32 accumulate in accb)
  for (int s=0;s<2;s++){
    const bf16* px = (s==0) ? px_y : px_x;
    for (int q=0;q<4;q++){
      fc1_lit<<<dim3(32768),blk,0,stream>>>(px, fc1_w, A, fc1_b, bn1s, bn1t, 256*q);
      if (q==0) fc2_lit<1><<<dim3(32768),blk,0,stream>>>(A, fc2_w, accb, 256*q);
      else      fc2_lit<0><<<dim3(32768),blk,0,stream>>>(A, fc2_w, accb, 256*q);
    }
    if (s==0) final_y<<<dim3(32768),blk,0,stream>>>(yin, accb, fc2_b, bn2s, bn2t, (float*)d_out);
    else      final_x<<<dim3(32768),blk,0,stream>>>(xin, accb, fc2_b, bn2s, bn2t, (float*)d_out);
  }
}